// Round 2
// baseline (3276.548 us; speedup 1.0000x reference)
//
#include <hip/hip_runtime.h>
#include <hip/hip_bf16.h>
#include <stdint.h>

#define BATCH 8192
#define SEQ   10
#define DM    1024
#define NH    8
#define HD    128
#define MROWS (BATCH*SEQ)   // 81920

typedef __bf16 bf16x8 __attribute__((ext_vector_type(8)));
typedef float  f32x4  __attribute__((ext_vector_type(4)));

// ---------- fp32 <-> bf16 split helpers (RNE) ----------
__device__ __forceinline__ unsigned short f2bf(float f) {
  unsigned u = __float_as_uint(f);
  unsigned r = u + 0x7FFFu + ((u >> 16) & 1u);
  return (unsigned short)(r >> 16);
}
__device__ __forceinline__ float bf2f(unsigned short h) {
  return __uint_as_float(((unsigned)h) << 16);
}

// ---------- split: fp32 -> bf16 hi + bf16 lo ----------
__global__ void split_kernel(const float* __restrict__ src,
                             unsigned short* __restrict__ hi,
                             unsigned short* __restrict__ lo, int n4) {
  int i = blockIdx.x * blockDim.x + threadIdx.x;
  int stride = gridDim.x * blockDim.x;
  for (; i < n4; i += stride) {
    float4 v = ((const float4*)src)[i];
    ushort4 h, l;
    h.x = f2bf(v.x); l.x = f2bf(v.x - bf2f(h.x));
    h.y = f2bf(v.y); l.y = f2bf(v.y - bf2f(h.y));
    h.z = f2bf(v.z); l.z = f2bf(v.z - bf2f(h.z));
    h.w = f2bf(v.w); l.w = f2bf(v.w - bf2f(h.w));
    ((ushort4*)hi)[i] = h;
    ((ushort4*)lo)[i] = l;
  }
}

__global__ void pack_bias_kernel(const float* __restrict__ bq, const float* __restrict__ bk,
                                 const float* __restrict__ bv, const float* __restrict__ bo,
                                 float* __restrict__ bias1, float* __restrict__ bias2) {
  int i = blockIdx.x * blockDim.x + threadIdx.x;
  if (i < 1024) {
    bias1[i]        = bq[i];
    bias1[1024 + i] = bk[i];
    bias1[2048 + i] = bv[i];
    bias2[i]        = bo[i];
  }
}

// ---------- async global->LDS, 16B per lane ----------
__device__ __forceinline__ void gload_lds16(const void* g, void* l) {
  __builtin_amdgcn_global_load_lds(
      (const __attribute__((address_space(1))) unsigned int*)g,
      (__attribute__((address_space(3))) unsigned int*)l, 16, 0, 0);
}

// ---------- split-bf16 NT GEMM: C[M][N] = sum_k A[m][k]*Bt[n][k] + bias[n] ----------
// 3-pass: hi*hi + lo*hi + hi*lo  (~4e-6 relative error vs fp32).
#define BM 128
#define BN 128
#define BK 32

__global__ __launch_bounds__(256)
void gemm_split_nt(const unsigned short* __restrict__ Ahi,
                   const unsigned short* __restrict__ Alo,
                   const unsigned short* __restrict__ Bhi,
                   const unsigned short* __restrict__ Blo,
                   const float* __restrict__ bias,
                   float* __restrict__ C,
                   int M, int N, int K) {
  __shared__ unsigned short sAh[BM * BK], sAl[BM * BK], sBh[BN * BK], sBl[BN * BK];

  const int tid  = threadIdx.x;
  const int wid  = tid >> 6;
  const int lane = tid & 63;
  const int wr   = wid >> 1, wc = wid & 1;   // 2x2 wave grid, 64x64 per wave
  const int m0   = blockIdx.y * BM;
  const int n0   = blockIdx.x * BN;

  const f32x4 zero = {0.f, 0.f, 0.f, 0.f};
  f32x4 acc[4][4];
#pragma unroll
  for (int i = 0; i < 4; ++i)
#pragma unroll
    for (int j = 0; j < 4; ++j) acc[i][j] = zero;

  // staging: tile = 128 rows x 64 bytes (BK=32 bf16). 8 chunks of 1KB; each wave stages 2.
  const int off0 = (wid * 2) * 1024 + lane * 16;  // byte offset in tile
  const int off1 = off0 + 1024;
  const int r0c = off0 >> 6, cb0 = off0 & 63;
  const int r1c = off1 >> 6, cb1 = off1 & 63;

  const size_t oA0 = ((size_t)(m0 + r0c) * K) * 2 + cb0;
  const size_t oA1 = ((size_t)(m0 + r1c) * K) * 2 + cb1;
  const size_t oB0 = ((size_t)(n0 + r0c) * K) * 2 + cb0;
  const size_t oB1 = ((size_t)(n0 + r1c) * K) * 2 + cb1;

  const char* pAh = (const char*)Ahi; const char* pAl = (const char*)Alo;
  const char* pBh = (const char*)Bhi; const char* pBl = (const char*)Blo;

  const int fr = lane & 15;        // row-in-frag (A) / col-in-frag (B)
  const int kg = lane >> 4;        // k-group (8 contiguous bf16 each)

  const int nIter = K / BK;
  for (int kt = 0; kt < nIter; ++kt) {
    __syncthreads();
    const size_t kb = (size_t)kt * (BK * 2);
    gload_lds16(pAh + oA0 + kb, (char*)sAh + off0);
    gload_lds16(pAh + oA1 + kb, (char*)sAh + off1);
    gload_lds16(pAl + oA0 + kb, (char*)sAl + off0);
    gload_lds16(pAl + oA1 + kb, (char*)sAl + off1);
    gload_lds16(pBh + oB0 + kb, (char*)sBh + off0);
    gload_lds16(pBh + oB1 + kb, (char*)sBh + off1);
    gload_lds16(pBl + oB0 + kb, (char*)sBl + off0);
    gload_lds16(pBl + oB1 + kb, (char*)sBl + off1);
    __syncthreads();

    bf16x8 a0[4], b0[4], t[4];
#pragma unroll
    for (int mi = 0; mi < 4; ++mi)
      a0[mi] = *(const bf16x8*)(const void*)(sAh + (wr * 64 + mi * 16 + fr) * BK + kg * 8);
#pragma unroll
    for (int ni = 0; ni < 4; ++ni)
      b0[ni] = *(const bf16x8*)(const void*)(sBh + (wc * 64 + ni * 16 + fr) * BK + kg * 8);

    // pass 1: hi * hi
#pragma unroll
    for (int mi = 0; mi < 4; ++mi)
#pragma unroll
      for (int ni = 0; ni < 4; ++ni)
        acc[mi][ni] = __builtin_amdgcn_mfma_f32_16x16x32_bf16(a0[mi], b0[ni], acc[mi][ni], 0, 0, 0);

    // pass 2: lo(A) * hi(B)
#pragma unroll
    for (int mi = 0; mi < 4; ++mi)
      t[mi] = *(const bf16x8*)(const void*)(sAl + (wr * 64 + mi * 16 + fr) * BK + kg * 8);
#pragma unroll
    for (int mi = 0; mi < 4; ++mi)
#pragma unroll
      for (int ni = 0; ni < 4; ++ni)
        acc[mi][ni] = __builtin_amdgcn_mfma_f32_16x16x32_bf16(t[mi], b0[ni], acc[mi][ni], 0, 0, 0);

    // pass 3: hi(A) * lo(B)
#pragma unroll
    for (int ni = 0; ni < 4; ++ni)
      t[ni] = *(const bf16x8*)(const void*)(sBl + (wc * 64 + ni * 16 + fr) * BK + kg * 8);
#pragma unroll
    for (int mi = 0; mi < 4; ++mi)
#pragma unroll
      for (int ni = 0; ni < 4; ++ni)
        acc[mi][ni] = __builtin_amdgcn_mfma_f32_16x16x32_bf16(a0[mi], t[ni], acc[mi][ni], 0, 0, 0);
  }

  // epilogue: C/D layout col=lane&15, row=(lane>>4)*4 + j  (m89-verified)
  const int rq = lane >> 4;
#pragma unroll
  for (int ni = 0; ni < 4; ++ni) {
    const int col = n0 + wc * 64 + ni * 16 + fr;
    const float bb = bias[col];
#pragma unroll
    for (int mi = 0; mi < 4; ++mi) {
      const int row = m0 + wr * 64 + mi * 16 + rq * 4;
#pragma unroll
      for (int j = 0; j < 4; ++j)
        C[(size_t)(row + j) * N + col] = acc[mi][ni][j] + bb;
    }
  }
}

// ---------- attention: one wave per (b,h); S=10, hd=128 ----------
__global__ __launch_bounds__(64)
void attn_kernel(const float* __restrict__ qkv,      // [rows][3072]: q|k|v (chunk-local)
                 const float* __restrict__ pos_bias, // [19]
                 unsigned short* __restrict__ ao_hi, // [rows][1024] (chunk-local)
                 unsigned short* __restrict__ ao_lo) {
  const int lane = threadIdx.x;
  const int bh = blockIdx.x;
  const int b = bh >> 3, h = bh & 7;
  const float* base = qkv + (size_t)b * (SEQ * 3072) + h * HD + 2 * lane;

  float2 qr[SEQ], kr[SEQ], vr[SEQ];
#pragma unroll
  for (int s = 0; s < SEQ; ++s) {
    qr[s] = *(const float2*)(base + (size_t)s * 3072);
    kr[s] = *(const float2*)(base + (size_t)s * 3072 + 1024);
    vr[s] = *(const float2*)(base + (size_t)s * 3072 + 2048);
  }
  float pb[2 * SEQ - 1];
#pragma unroll
  for (int i = 0; i < 2 * SEQ - 1; ++i) pb[i] = pos_bias[i];

  const float scale = 0.08838834764831845f;  // 128^-0.5

#pragma unroll
  for (int qi = 0; qi < SEQ; ++qi) {
    float srow[SEQ];
#pragma unroll
    for (int kj = 0; kj < SEQ; ++kj) {
      float p = qr[qi].x * kr[kj].x + qr[qi].y * kr[kj].y;
      p += __shfl_xor(p, 32); p += __shfl_xor(p, 16); p += __shfl_xor(p, 8);
      p += __shfl_xor(p, 4);  p += __shfl_xor(p, 2);  p += __shfl_xor(p, 1);
      srow[kj] = p * scale + pb[kj - qi + SEQ - 1];
    }
    float m = srow[0];
#pragma unroll
    for (int kj = 1; kj < SEQ; ++kj) m = fmaxf(m, srow[kj]);
    float sum = 0.f;
#pragma unroll
    for (int kj = 0; kj < SEQ; ++kj) { srow[kj] = expf(srow[kj] - m); sum += srow[kj]; }
    const float inv = 1.f / sum;
    float ax = 0.f, ay = 0.f;
#pragma unroll
    for (int kj = 0; kj < SEQ; ++kj) { ax += srow[kj] * vr[kj].x; ay += srow[kj] * vr[kj].y; }
    ax *= inv; ay *= inv;

    const unsigned short hx = f2bf(ax), hy = f2bf(ay);
    const unsigned short lx = f2bf(ax - bf2f(hx)), ly = f2bf(ay - bf2f(hy));
    const size_t o = ((size_t)b * SEQ + qi) * DM + h * HD + 2 * lane;
    *(unsigned*)(ao_hi + o) = (unsigned)hx | ((unsigned)hy << 16);
    *(unsigned*)(ao_lo + o) = (unsigned)lx | ((unsigned)ly << 16);
  }
}

extern "C" void kernel_launch(void* const* d_in, const int* in_sizes, int n_in,
                              void* d_out, int out_size, void* d_ws, size_t ws_size,
                              hipStream_t stream) {
  const float* x  = (const float*)d_in[0];
  const float* Wq = (const float*)d_in[1];
  const float* bq = (const float*)d_in[2];
  const float* Wk = (const float*)d_in[3];
  const float* bk = (const float*)d_in[4];
  const float* Wv = (const float*)d_in[5];
  const float* bv = (const float*)d_in[6];
  const float* Wo = (const float*)d_in[7];
  const float* bo = (const float*)d_in[8];
  const float* pos_bias = (const float*)d_in[9];
  float* out = (float*)d_out;

  char* p = (char*)d_ws;
  auto alloc = [&](size_t bytes) {
    char* r = p;
    p += (bytes + 255) & ~(size_t)255;
    return r;
  };

  // ---- fixed: weight splits + biases (~17 MB) ----
  unsigned short* w1h = (unsigned short*)alloc((size_t)3 * DM * DM * 2);
  unsigned short* w1l = (unsigned short*)alloc((size_t)3 * DM * DM * 2);
  unsigned short* w2h = (unsigned short*)alloc((size_t)DM * DM * 2);
  unsigned short* w2l = (unsigned short*)alloc((size_t)DM * DM * 2);
  float* bias1 = (float*)alloc(3072 * 4);
  float* bias2 = (float*)alloc(1024 * 4);

  // ---- adaptive chunking over rows (multiple of lcm(BM,SEQ)*... = 640) ----
  // per-row: xh/xl (2*2048 B) + qkv (12288 B) = 16384 B
  size_t used = (size_t)(p - (char*)d_ws);
  size_t avail = (ws_size > used + 8192) ? (ws_size - used - 8192) : 0;
  long maxrows = (long)(avail / 16384);
  int cr = (int)((maxrows / 640) * 640);
  if (cr < 640) cr = 640;          // below this nothing fits; proceed anyway
  if (cr > MROWS) cr = MROWS;

  unsigned short* xh  = (unsigned short*)alloc((size_t)cr * DM * 2);
  unsigned short* xl  = (unsigned short*)alloc((size_t)cr * DM * 2);
  float*          qkv = (float*)alloc((size_t)cr * 3 * DM * 4);

  // ---- weight prep (once per call) ----
  split_kernel<<<256, 256, 0, stream>>>(Wq, w1h, w1l, DM * DM / 4);
  split_kernel<<<256, 256, 0, stream>>>(Wk, w1h + DM * DM, w1l + DM * DM, DM * DM / 4);
  split_kernel<<<256, 256, 0, stream>>>(Wv, w1h + 2 * DM * DM, w1l + 2 * DM * DM, DM * DM / 4);
  split_kernel<<<256, 256, 0, stream>>>(Wo, w2h, w2l, DM * DM / 4);
  pack_bias_kernel<<<4, 256, 0, stream>>>(bq, bk, bv, bo, bias1, bias2);

  // ---- chunked pipeline: split x -> QKV GEMM -> attention -> output GEMM ----
  for (int r0 = 0; r0 < MROWS; r0 += cr) {
    const int m = (MROWS - r0 < cr) ? (MROWS - r0) : cr;
    const int n4 = m * (DM / 4);
    int sgrid = (n4 + 255) / 256; if (sgrid > 2048) sgrid = 2048;

    split_kernel<<<sgrid, 256, 0, stream>>>(x + (size_t)r0 * DM, xh, xl, n4);

    dim3 g1(3 * DM / BN, m / BM);
    gemm_split_nt<<<g1, 256, 0, stream>>>(xh, xl, w1h, w1l, bias1, qkv, m, 3 * DM, DM);

    // attention output aliases xh/xl (x-split dead after GEMM1; stream-ordered)
    attn_kernel<<<(m / SEQ) * NH, 64, 0, stream>>>(qkv, pos_bias, xh, xl);

    dim3 g2(DM / BN, m / BM);
    gemm_split_nt<<<g2, 256, 0, stream>>>(xh, xl, w2h, w2l, bias2,
                                          out + (size_t)r0 * DM, m, DM, DM);
  }
}

// Round 3
// 3027.690 us; speedup vs baseline: 1.0822x; 1.0822x over previous
//
#include <hip/hip_runtime.h>
#include <hip/hip_bf16.h>
#include <stdint.h>

#define BATCH 8192
#define SEQ   10
#define DM    1024
#define NH    8
#define HD    128
#define MROWS (BATCH*SEQ)   // 81920

typedef __bf16 bf16x8 __attribute__((ext_vector_type(8)));
typedef float  f32x4  __attribute__((ext_vector_type(4)));

// ---------- fp32 <-> bf16 split helpers (RNE) ----------
__device__ __forceinline__ unsigned short f2bf(float f) {
  unsigned u = __float_as_uint(f);
  unsigned r = u + 0x7FFFu + ((u >> 16) & 1u);
  return (unsigned short)(r >> 16);
}
__device__ __forceinline__ float bf2f(unsigned short h) {
  return __uint_as_float(((unsigned)h) << 16);
}

// ---------- split: fp32 -> bf16 hi + bf16 lo ----------
__global__ void split_kernel(const float* __restrict__ src,
                             unsigned short* __restrict__ hi,
                             unsigned short* __restrict__ lo, int n4) {
  int i = blockIdx.x * blockDim.x + threadIdx.x;
  int stride = gridDim.x * blockDim.x;
  for (; i < n4; i += stride) {
    float4 v = ((const float4*)src)[i];
    ushort4 h, l;
    h.x = f2bf(v.x); l.x = f2bf(v.x - bf2f(h.x));
    h.y = f2bf(v.y); l.y = f2bf(v.y - bf2f(h.y));
    h.z = f2bf(v.z); l.z = f2bf(v.z - bf2f(h.z));
    h.w = f2bf(v.w); l.w = f2bf(v.w - bf2f(h.w));
    ((ushort4*)hi)[i] = h;
    ((ushort4*)lo)[i] = l;
  }
}

__global__ void pack_bias_kernel(const float* __restrict__ bq, const float* __restrict__ bk,
                                 const float* __restrict__ bv, const float* __restrict__ bo,
                                 float* __restrict__ bias1, float* __restrict__ bias2) {
  int i = blockIdx.x * blockDim.x + threadIdx.x;
  if (i < 1024) {
    bias1[i]        = bq[i];
    bias1[1024 + i] = bk[i];
    bias1[2048 + i] = bv[i];
    bias2[i]        = bo[i];
  }
}

// ---------- async global->LDS, 16B per lane ----------
__device__ __forceinline__ void gload_lds16(const void* g, void* l) {
  __builtin_amdgcn_global_load_lds(
      (const __attribute__((address_space(1))) unsigned int*)g,
      (__attribute__((address_space(3))) unsigned int*)l, 16, 0, 0);
}

// ---------- split-bf16 NT GEMM: C[M][N] = sum_k A[m][k]*Bt[n][k] + bias[n] ----------
// 3-pass: hi*hi + lo*hi + hi*lo. 2-phase double-buffered staging; in-row XOR swizzle
// (slot ^= row&3) applied on BOTH the global source and the ds_read (ERRATA#21).
#define BM 128
#define BN 128
#define BK 32
// per-operand tile: 128 rows x 64B = 8KB. 4 operands x 2 sets = 64KB LDS.

__global__ __launch_bounds__(256)
void gemm_split_nt(const unsigned short* __restrict__ Ahi,
                   const unsigned short* __restrict__ Alo,
                   const unsigned short* __restrict__ Bhi,
                   const unsigned short* __restrict__ Blo,
                   const float* __restrict__ bias,
                   float* __restrict__ C,
                   int M, int N, int K) {
  __shared__ char smem[2 * 4 * 8192];   // [set][op][8KB]

  const int tid  = threadIdx.x;
  const int wid  = tid >> 6;
  const int lane = tid & 63;
  const int wr   = wid >> 1, wc = wid & 1;   // 2x2 wave grid, 64x64 per wave
  const int m0   = blockIdx.y * BM;
  const int n0   = blockIdx.x * BN;

  const f32x4 zero = {0.f, 0.f, 0.f, 0.f};
  f32x4 acc[4][4];
#pragma unroll
  for (int i = 0; i < 4; ++i)
#pragma unroll
    for (int j = 0; j < 4; ++j) acc[i][j] = zero;

  // ---- staging geometry (per wave: 2 chunks of 1KB per operand) ----
  const int ldsoff0 = wid * 2048 + lane * 16;
  const int ldsoff1 = ldsoff0 + 1024;
  // chunk rows: r = wid*32 + j*16 + (lane>>2); source slot = (lane&3) ^ (row&3)
  const int ss   = (lane & 3) ^ ((lane >> 2) & 3);       // swizzled k-slot (16B units)
  const int r0c  = wid * 32 + (lane >> 2);
  const int r1c  = r0c + 16;

  const size_t bA0 = (size_t)(m0 + r0c) * (K * 2) + ss * 16;
  const size_t bA1 = (size_t)(m0 + r1c) * (K * 2) + ss * 16;
  const size_t bB0 = (size_t)(n0 + r0c) * (K * 2) + ss * 16;
  const size_t bB1 = (size_t)(n0 + r1c) * (K * 2) + ss * 16;

  const char* pAh = (const char*)Ahi; const char* pAl = (const char*)Alo;
  const char* pBh = (const char*)Bhi; const char* pBl = (const char*)Blo;

  const int fr  = lane & 15;                 // row-in-frag (A) / col-in-frag (B)
  const int kg  = lane >> 4;                 // k-group (8 contiguous bf16)
  const int kgs = kg ^ (fr & 3);             // swizzled read slot

  const int nIter = K / BK;

#define STAGE(set, kt)                                                        \
  {                                                                           \
    char* dst = smem + (set) * 32768;                                         \
    const size_t kb = (size_t)(kt) * (BK * 2);                                \
    gload_lds16(pAh + bA0 + kb, dst + ldsoff0);                               \
    gload_lds16(pAh + bA1 + kb, dst + ldsoff1);                               \
    gload_lds16(pAl + bA0 + kb, dst + 8192 + ldsoff0);                        \
    gload_lds16(pAl + bA1 + kb, dst + 8192 + ldsoff1);                        \
    gload_lds16(pBh + bB0 + kb, dst + 16384 + ldsoff0);                       \
    gload_lds16(pBh + bB1 + kb, dst + 16384 + ldsoff1);                       \
    gload_lds16(pBl + bB0 + kb, dst + 24576 + ldsoff0);                       \
    gload_lds16(pBl + bB1 + kb, dst + 24576 + ldsoff1);                       \
  }

  // prologue: fill set 0
  STAGE(0, 0);
  __syncthreads();

  for (int kt = 0; kt < nIter; ++kt) {
    const int cur = kt & 1;
    if (kt + 1 < nIter) STAGE(cur ^ 1, kt + 1);   // prefetch next (hidden under MFMA)

    const char* base = smem + cur * 32768;
    const char* sAh = base;
    const char* sAl = base + 8192;
    const char* sBh = base + 16384;
    const char* sBl = base + 24576;

    bf16x8 a0[4], b0[4], t[4];
#pragma unroll
    for (int mi = 0; mi < 4; ++mi)
      a0[mi] = *(const bf16x8*)(sAh + (wr * 64 + mi * 16 + fr) * 64 + kgs * 16);
#pragma unroll
    for (int ni = 0; ni < 4; ++ni)
      b0[ni] = *(const bf16x8*)(sBh + (wc * 64 + ni * 16 + fr) * 64 + kgs * 16);

    // pass 1: hi * hi
#pragma unroll
    for (int mi = 0; mi < 4; ++mi)
#pragma unroll
      for (int ni = 0; ni < 4; ++ni)
        acc[mi][ni] = __builtin_amdgcn_mfma_f32_16x16x32_bf16(a0[mi], b0[ni], acc[mi][ni], 0, 0, 0);

    // pass 2: lo(A) * hi(B)
#pragma unroll
    for (int mi = 0; mi < 4; ++mi)
      t[mi] = *(const bf16x8*)(sAl + (wr * 64 + mi * 16 + fr) * 64 + kgs * 16);
#pragma unroll
    for (int mi = 0; mi < 4; ++mi)
#pragma unroll
      for (int ni = 0; ni < 4; ++ni)
        acc[mi][ni] = __builtin_amdgcn_mfma_f32_16x16x32_bf16(t[mi], b0[ni], acc[mi][ni], 0, 0, 0);

    // pass 3: hi(A) * lo(B)
#pragma unroll
    for (int ni = 0; ni < 4; ++ni)
      t[ni] = *(const bf16x8*)(sBl + (wc * 64 + ni * 16 + fr) * 64 + kgs * 16);
#pragma unroll
    for (int mi = 0; mi < 4; ++mi)
#pragma unroll
      for (int ni = 0; ni < 4; ++ni)
        acc[mi][ni] = __builtin_amdgcn_mfma_f32_16x16x32_bf16(a0[mi], t[ni], acc[mi][ni], 0, 0, 0);

    __syncthreads();   // drains prefetch vmcnt + read lgkmcnt; set swap safe
  }
#undef STAGE

  // epilogue: C/D layout col=lane&15, row=(lane>>4)*4 + j  (m89-verified)
  const int rq = lane >> 4;
#pragma unroll
  for (int ni = 0; ni < 4; ++ni) {
    const int col = n0 + wc * 64 + ni * 16 + fr;
    const float bb = bias[col];
#pragma unroll
    for (int mi = 0; mi < 4; ++mi) {
      const int row = m0 + wr * 64 + mi * 16 + rq * 4;
#pragma unroll
      for (int j = 0; j < 4; ++j)
        C[(size_t)(row + j) * N + col] = acc[mi][ni][j] + bb;
    }
  }
}

// ---------- attention: 4 waves/block, one wave per (b,h); S=10, hd=128 ----------
__global__ __launch_bounds__(256)
void attn_kernel(const float* __restrict__ qkv,      // [rows][3072]: q|k|v (chunk-local)
                 const float* __restrict__ pos_bias, // [19]
                 unsigned short* __restrict__ ao_hi, // [rows][1024] (chunk-local)
                 unsigned short* __restrict__ ao_lo) {
  const int lane = threadIdx.x & 63;
  const int bh = blockIdx.x * 4 + (threadIdx.x >> 6);
  const int b = bh >> 3, h = bh & 7;
  const float* base = qkv + (size_t)b * (SEQ * 3072) + h * HD + 2 * lane;

  float2 qr[SEQ], kr[SEQ], vr[SEQ];
#pragma unroll
  for (int s = 0; s < SEQ; ++s) {
    qr[s] = *(const float2*)(base + (size_t)s * 3072);
    kr[s] = *(const float2*)(base + (size_t)s * 3072 + 1024);
    vr[s] = *(const float2*)(base + (size_t)s * 3072 + 2048);
  }
  float pb[2 * SEQ - 1];
#pragma unroll
  for (int i = 0; i < 2 * SEQ - 1; ++i) pb[i] = pos_bias[i];

  const float scale = 0.08838834764831845f;  // 128^-0.5

#pragma unroll
  for (int qi = 0; qi < SEQ; ++qi) {
    float srow[SEQ];
#pragma unroll
    for (int kj = 0; kj < SEQ; ++kj) {
      float p = qr[qi].x * kr[kj].x + qr[qi].y * kr[kj].y;
      p += __shfl_xor(p, 32); p += __shfl_xor(p, 16); p += __shfl_xor(p, 8);
      p += __shfl_xor(p, 4);  p += __shfl_xor(p, 2);  p += __shfl_xor(p, 1);
      srow[kj] = p * scale + pb[kj - qi + SEQ - 1];
    }
    float m = srow[0];
#pragma unroll
    for (int kj = 1; kj < SEQ; ++kj) m = fmaxf(m, srow[kj]);
    float sum = 0.f;
#pragma unroll
    for (int kj = 0; kj < SEQ; ++kj) { srow[kj] = expf(srow[kj] - m); sum += srow[kj]; }
    const float inv = 1.f / sum;
    float ax = 0.f, ay = 0.f;
#pragma unroll
    for (int kj = 0; kj < SEQ; ++kj) { ax += srow[kj] * vr[kj].x; ay += srow[kj] * vr[kj].y; }
    ax *= inv; ay *= inv;

    const unsigned short hx = f2bf(ax), hy = f2bf(ay);
    const unsigned short lx = f2bf(ax - bf2f(hx)), ly = f2bf(ay - bf2f(hy));
    const size_t o = ((size_t)b * SEQ + qi) * DM + h * HD + 2 * lane;
    *(unsigned*)(ao_hi + o) = (unsigned)hx | ((unsigned)hy << 16);
    *(unsigned*)(ao_lo + o) = (unsigned)lx | ((unsigned)ly << 16);
  }
}

extern "C" void kernel_launch(void* const* d_in, const int* in_sizes, int n_in,
                              void* d_out, int out_size, void* d_ws, size_t ws_size,
                              hipStream_t stream) {
  const float* x  = (const float*)d_in[0];
  const float* Wq = (const float*)d_in[1];
  const float* bq = (const float*)d_in[2];
  const float* Wk = (const float*)d_in[3];
  const float* bk = (const float*)d_in[4];
  const float* Wv = (const float*)d_in[5];
  const float* bv = (const float*)d_in[6];
  const float* Wo = (const float*)d_in[7];
  const float* bo = (const float*)d_in[8];
  const float* pos_bias = (const float*)d_in[9];
  float* out = (float*)d_out;

  char* p = (char*)d_ws;
  auto alloc = [&](size_t bytes) {
    char* r = p;
    p += (bytes + 255) & ~(size_t)255;
    return r;
  };

  // ---- fixed: weight splits + biases (~17 MB) ----
  unsigned short* w1h = (unsigned short*)alloc((size_t)3 * DM * DM * 2);
  unsigned short* w1l = (unsigned short*)alloc((size_t)3 * DM * DM * 2);
  unsigned short* w2h = (unsigned short*)alloc((size_t)DM * DM * 2);
  unsigned short* w2l = (unsigned short*)alloc((size_t)DM * DM * 2);
  float* bias1 = (float*)alloc(3072 * 4);
  float* bias2 = (float*)alloc(1024 * 4);

  // ---- adaptive chunking over rows (multiple of lcm(BM,SEQ) = 640) ----
  // per-row: xh/xl (2*2048 B) + qkv (12288 B) = 16384 B
  size_t used = (size_t)(p - (char*)d_ws);
  size_t avail = (ws_size > used + 8192) ? (ws_size - used - 8192) : 0;
  long maxrows = (long)(avail / 16384);
  int cr = (int)((maxrows / 640) * 640);
  if (cr < 640) cr = 640;
  if (cr > MROWS) cr = MROWS;

  unsigned short* xh  = (unsigned short*)alloc((size_t)cr * DM * 2);
  unsigned short* xl  = (unsigned short*)alloc((size_t)cr * DM * 2);
  float*          qkv = (float*)alloc((size_t)cr * 3 * DM * 4);

  // ---- weight prep (once per call) ----
  split_kernel<<<256, 256, 0, stream>>>(Wq, w1h, w1l, DM * DM / 4);
  split_kernel<<<256, 256, 0, stream>>>(Wk, w1h + DM * DM, w1l + DM * DM, DM * DM / 4);
  split_kernel<<<256, 256, 0, stream>>>(Wv, w1h + 2 * DM * DM, w1l + 2 * DM * DM, DM * DM / 4);
  split_kernel<<<256, 256, 0, stream>>>(Wo, w2h, w2l, DM * DM / 4);
  pack_bias_kernel<<<4, 256, 0, stream>>>(bq, bk, bv, bo, bias1, bias2);

  // ---- chunked pipeline: split x -> QKV GEMM -> attention -> output GEMM ----
  for (int r0 = 0; r0 < MROWS; r0 += cr) {
    const int m = (MROWS - r0 < cr) ? (MROWS - r0) : cr;
    const int n4 = m * (DM / 4);
    int sgrid = (n4 + 255) / 256; if (sgrid > 2048) sgrid = 2048;

    split_kernel<<<sgrid, 256, 0, stream>>>(x + (size_t)r0 * DM, xh, xl, n4);

    dim3 g1(3 * DM / BN, m / BM);
    gemm_split_nt<<<g1, 256, 0, stream>>>(xh, xl, w1h, w1l, bias1, qkv, m, 3 * DM, DM);

    // attention output aliases xh/xl (x-split dead after GEMM1; stream-ordered)
    attn_kernel<<<(m / SEQ) * NH / 4, 256, 0, stream>>>(qkv, pos_bias, xh, xl);

    dim3 g2(DM / BN, m / BM);
    gemm_split_nt<<<g2, 256, 0, stream>>>(xh, xl, w2h, w2l, bias2,
                                          out + (size_t)r0 * DM, m, DM, DM);
  }
}